// Round 3
// baseline (877.608 us; speedup 1.0000x reference)
//
#include <hip/hip_runtime.h>
#include <math.h>

#define NROW 8192
#define DDIM 256
#define BM 128
#define BN 64           // column-half blocks: wave tile 64x32 -> 32 acc regs
#define BK 128
#define NT_SYM 2080     // 64*65/2 lower-triangular 128x128 logical tiles
#define NT_FULL 4096
#define NT_TOTAL (2 * NT_SYM + NT_FULL)   // 8256 logical tiles
#define GRID (2 * NT_TOTAL)               // 2 column-halves each

typedef __attribute__((ext_vector_type(4)))  float f32x4;
typedef __attribute__((ext_vector_type(16))) float f32x16;
typedef __attribute__((ext_vector_type(4)))  int   i32x4;
typedef __attribute__((ext_vector_type(8)))  int   i32x8;
typedef __attribute__((address_space(3))) unsigned int lds_u32;
typedef const __attribute__((address_space(1))) unsigned int glb_u32;

// DPP row_ror butterfly add: after ror 1,2,4,8 every lane of each 16-lane row
// holds the row sum. VALU pipe only — no DS traffic.
template <int CTRL>
static __device__ inline float dpp_ror_add(float v) {
    int s = __float_as_int(v);
    int r = __builtin_amdgcn_update_dpp(0, s, CTRL, 0xF, 0xF, true);
    return v + __int_as_float(r);
}
static __device__ inline float row16_sum(float v) {
    v = dpp_ror_add<0x121>(v);
    v = dpp_ror_add<0x122>(v);
    v = dpp_ror_add<0x124>(v);
    v = dpp_ror_add<0x128>(v);
    return v;
}

// Pack 4 floats -> 4 fp8 e4m3 bytes (HW cvt, OCP on gfx950 — self-consistent
// with the fp8 MFMA's decode).
static __device__ inline unsigned int pack_fp8x4(float a, float b, float c, float d) {
    int p = __builtin_amdgcn_cvt_pk_fp8_f32(a, b, 0, false);
    p = __builtin_amdgcn_cvt_pk_fp8_f32(c, d, p, true);
    return (unsigned int)p;
}

// One wave per row: L2-normalize H1/H2 rows, scale by sqrt(2*log2(e)) so the
// fp8 Gram entries come out as 2*log2(e)*s -> exp(2s) == exp2(acc).
// diag[row] = 2*dot(z1n,z2n) fp32 (exact). Zero-inits rowsums and out.
__global__ __launch_bounds__(256) void normalize_kernel(
        const float* __restrict__ h1, const float* __restrict__ h2,
        unsigned char* __restrict__ z1b, unsigned char* __restrict__ z2b,
        float* __restrict__ diag,
        float* __restrict__ rs1, float* __restrict__ rs2,
        float* __restrict__ rbr, float* __restrict__ rbc,
        float* __restrict__ out) {
    int wave = threadIdx.x >> 6;
    int lane = threadIdx.x & 63;
    int row  = blockIdx.x * 4 + wave;
    if (blockIdx.x == 0 && threadIdx.x == 0) out[0] = 0.f;
    const float4* p1 = (const float4*)(h1 + (size_t)row * DDIM);
    const float4* p2 = (const float4*)(h2 + (size_t)row * DDIM);
    float4 a = p1[lane];
    float4 b = p2[lane];
    float s1 = a.x*a.x + a.y*a.y + a.z*a.z + a.w*a.w;
    float s2 = b.x*b.x + b.y*b.y + b.z*b.z + b.w*b.w;
    #pragma unroll
    for (int m = 1; m < 64; m <<= 1) { s1 += __shfl_xor(s1, m); s2 += __shfl_xor(s2, m); }
    float r1 = 1.0f / fmaxf(sqrtf(s1), 1e-12f);
    float r2 = 1.0f / fmaxf(sqrtf(s2), 1e-12f);
    float n1x = a.x*r1, n1y = a.y*r1, n1z = a.z*r1, n1w = a.w*r1;
    float n2x = b.x*r2, n2y = b.y*r2, n2z = b.z*r2, n2w = b.w*r2;
    float dt = n1x*n2x + n1y*n2y + n1z*n2z + n1w*n2w;
    #pragma unroll
    for (int m = 1; m < 64; m <<= 1) dt += __shfl_xor(dt, m);
    if (lane == 0) {
        diag[row] = 2.0f * dt;
        rs1[row] = 0.f; rs2[row] = 0.f; rbr[row] = 0.f; rbc[row] = 0.f;
    }
    const float SC = 1.69864364f;   // sqrt(2 * log2(e))
    ((unsigned int*)(z1b + (size_t)row * DDIM))[lane] =
        pack_fp8x4(n1x*SC, n1y*SC, n1z*SC, n1w*SC);
    ((unsigned int*)(z2b + (size_t)row * DDIM))[lane] =
        pack_fp8x4(n2x*SC, n2y*SC, n2z*SC, n2w*SC);
}

// R7: occupancy-first restructure. Evidence R4/R5/R6: dur x occupancy ~const
// (latency-bound; throughput ~ resident waves). The 64-reg accumulator
// (64x64 wave tile) was capping blocks/CU at 2-4. Now: block = 128x64
// (column-half of the logical 128x128 tile; blockIdx = tile*2 + half),
// wave tile 64x32 -> acc = 2 x f32x16 = 32 regs. Target 6 blocks/CU
// (launch_bounds(256,6): <=85 regs; LDS 24 KB -> 6 fit in 160 KB).
// Scaled 32x32x64 fp8 MFMA kept (measured at the ~4.7 PF rate).
// Cost: A tile staged once per half (stage traffic x1.5) — L2-absorbed.
//
// LDS: rows are 128 B = 8 16B-granules = one full 32-bank line. Physical
// granule p of row r holds logical granule p ^ (r&7) (XOR on the global
// address side of the DMA; LDS dest linear as global_load_lds requires).
// b128 read beats (8 lanes, 8 consecutive rows) hit all 8 granules ->
// conflict-free. Epilogue: no cross-lane shuffles — the 2 (or 2x2) lanes
// holding partials for the same row/col just issue atomics directly.
__global__ __launch_bounds__(256, 6) void expsum_kernel(
        const unsigned char* __restrict__ z1, const unsigned char* __restrict__ z2,
        float* __restrict__ rs1, float* __restrict__ rs2,
        float* __restrict__ rbr, float* __restrict__ rbc) {
    int t  = blockIdx.x >> 1;
    int ch = blockIdx.x & 1;           // which 64-col half of the 128x128 tile
    int kind, tt;
    if (t < NT_SYM)            { kind = 0; tt = t; }
    else if (t < 2 * NT_SYM)   { kind = 1; tt = t - NT_SYM; }
    else                       { kind = 2; tt = t - 2 * NT_SYM; }

    int by, bx;
    const unsigned char *Ap, *Bp;
    float *rowsum, *colsum;
    if (kind == 2) {
        by = tt >> 6; bx = tt & 63;
        Ap = z1; Bp = z2; rowsum = rbr; colsum = rbc;
    } else {
        by = (int)((sqrtf(8.0f * (float)tt + 1.0f) - 1.0f) * 0.5f);
        while ((by + 1) * (by + 2) / 2 <= tt) ++by;
        while (by * (by + 1) / 2 > tt) --by;
        bx = tt - by * (by + 1) / 2;          // bx <= by
        const unsigned char* z = (kind == 0) ? z1 : z2;
        Ap = z; Bp = z;
        rowsum = (kind == 0) ? rs1 : rs2;
        colsum = (bx == by) ? nullptr : rowsum;
    }

    const int rt = by * BM;
    const int ct = bx * BM + ch * BN;    // global col base of this half

    __shared__ __align__(16) unsigned char lA[BM * BK];  // 16 KB
    __shared__ __align__(16) unsigned char lB[BN * BK];  // 8 KB

    const int tid  = threadIdx.x;
    const int lane = tid & 63;
    const int wid  = tid >> 6;
    const int wr   = wid & 1;            // 64-row half
    const int wc   = wid >> 1;           // 32-col quarter (of the 64-col tile)
    const int l31  = lane & 31;
    const int kh   = lane >> 5;          // k-half of the 64-wide k-step

    // DMA lane mapping: 8 lanes per 128-B row, 8 rows per wave-instruction.
    const int srow = lane >> 3;          // row within 8-row group
    const int sgt  = lane & 7;           // physical 16B granule (= DMA slot)

    const int sw16 = (l31 & 7);          // row-swizzle key for reads

    const int aoff0 = (wr * 64 + l31) * BK;          // mi=0 rows
    const int aoff1 = aoff0 + 32 * BK;               // mi=1 rows
    const int boff  = (wc * 32 + l31) * BK;

    f32x16 acc0, acc1;
    #pragma unroll
    for (int r = 0; r < 16; ++r) { acc0[r] = 0.f; acc1[r] = 0.f; }

    for (int kt = 0; kt < DDIM; kt += BK) {
        // Stage A (128x128B: 16 DMAs, 4/wave) and B (64x128B: 8 DMAs, 2/wave).
        #pragma unroll
        for (int p = 0; p < 4; ++p) {
            int r0 = (p * 4 + wid) * 8;
            int r  = r0 + srow;
            int gg = sgt ^ (r & 7);
            const unsigned char* ga = Ap + (size_t)(rt + r) * DDIM + kt + gg * 16;
            __builtin_amdgcn_global_load_lds((glb_u32*)ga, (lds_u32*)(lA + r0 * BK), 16, 0, 0);
        }
        #pragma unroll
        for (int p = 0; p < 2; ++p) {
            int r0 = (p * 4 + wid) * 8;
            int r  = r0 + srow;
            int gg = sgt ^ (r & 7);
            const unsigned char* gb = Bp + (size_t)(ct + r) * DDIM + kt + gg * 16;
            __builtin_amdgcn_global_load_lds((glb_u32*)gb, (lds_u32*)(lB + r0 * BK), 16, 0, 0);
        }
        __syncthreads();
        #pragma unroll
        for (int ks = 0; ks < 2; ++ks) {            // 2 x K=64 per k-tile
            const int g0   = ks * 4 + kh * 2;       // logical even granule
            const int off0 = (g0 ^ sw16) * 16;
            const int off1 = off0 ^ 16;             // odd partner granule
            i32x4 alo0 = *(const i32x4*)(lA + aoff0 + off0);
            i32x4 ahi0 = *(const i32x4*)(lA + aoff0 + off1);
            i32x4 alo1 = *(const i32x4*)(lA + aoff1 + off0);
            i32x4 ahi1 = *(const i32x4*)(lA + aoff1 + off1);
            i32x4 blo  = *(const i32x4*)(lB + boff  + off0);
            i32x4 bhi  = *(const i32x4*)(lB + boff  + off1);
            i32x8 a0 = (i32x8){alo0[0], alo0[1], alo0[2], alo0[3],
                               ahi0[0], ahi0[1], ahi0[2], ahi0[3]};
            i32x8 a1 = (i32x8){alo1[0], alo1[1], alo1[2], alo1[3],
                               ahi1[0], ahi1[1], ahi1[2], ahi1[3]};
            i32x8 bv = (i32x8){blo[0], blo[1], blo[2], blo[3],
                               bhi[0], bhi[1], bhi[2], bhi[3]};
            acc0 = __builtin_amdgcn_mfma_scale_f32_32x32x64_f8f6f4(
                a0, bv, acc0, 0, 0, 0, 0x7F7F7F7F, 0, 0x7F7F7F7F);
            acc1 = __builtin_amdgcn_mfma_scale_f32_32x32x64_f8f6f4(
                a1, bv, acc1, 0, 0, 0, 0x7F7F7F7F, 0, 0x7F7F7F7F);
        }
        __syncthreads();
    }

    // C/D layout (32x32): col = lane&31, row = (reg&3) + 8*(reg>>2) + 4*kh.
    // acc = 2*log2e*s -> raw v_exp_f32. No shuffles: lanes l31==0 and l31==16
    // both hold a 16-col partial for the same row -> both atomicAdd (L2
    // coalesces); colsum partials live per-lane per kh-half -> all 64 lanes
    // atomicAdd (2 lanes per col address).
    float colpart = 0.f;
    const int rbase = rt + wr * 64 + 4 * kh;
    #pragma unroll
    for (int r = 0; r < 16; ++r) {
        float e0 = __builtin_amdgcn_exp2f(acc0[r]);
        float e1 = __builtin_amdgcn_exp2f(acc1[r]);
        colpart += e0 + e1;
        float rp0 = row16_sum(e0);
        float rp1 = row16_sum(e1);
        if ((lane & 15) == 0) {
            int grow = rbase + (r & 3) + 8 * (r >> 2);
            atomicAdd(&rowsum[grow], rp0);
            atomicAdd(&rowsum[grow + 32], rp1);
        }
    }
    if (colsum) {
        atomicAdd(&colsum[ct + wc * 32 + l31], colpart);
    }
}

// 32 blocks x 256 threads, one row each; block-reduce then one atomicAdd.
__global__ __launch_bounds__(256) void finalize_kernel(
        const float* __restrict__ rs1, const float* __restrict__ rs2,
        const float* __restrict__ rbr, const float* __restrict__ rbc,
        const float* __restrict__ diag, float* __restrict__ out) {
    __shared__ float s4[4];
    const float E2 = 7.38905609893065f;   // exp(1/tau), tau=0.5
    int i = blockIdx.x * 256 + threadIdx.x;
    float den1 = rs1[i] + rbr[i] - E2;
    float den2 = rs2[i] + rbc[i] - E2;
    float v = 0.5f * (logf(den1) + logf(den2)) - diag[i];
    #pragma unroll
    for (int m = 1; m < 64; m <<= 1) v += __shfl_xor(v, m);
    if ((threadIdx.x & 63) == 0) s4[threadIdx.x >> 6] = v;
    __syncthreads();
    if (threadIdx.x == 0) {
        float t = (s4[0] + s4[1] + s4[2] + s4[3]) * (1.0f / (float)NROW);
        atomicAdd(out, t);
    }
}

extern "C" void kernel_launch(void* const* d_in, const int* in_sizes, int n_in,
                              void* d_out, int out_size, void* d_ws, size_t ws_size,
                              hipStream_t stream) {
    const float* h1 = (const float*)d_in[0];
    const float* h2 = (const float*)d_in[1];
    float* out = (float*)d_out;

    char* ws = (char*)d_ws;
    unsigned char* z1b = (unsigned char*)ws;                             // 2 MB
    unsigned char* z2b = (unsigned char*)(ws + (size_t)NROW * DDIM);     // 2 MB
    float* sums = (float*)(ws + (size_t)2 * NROW * DDIM);
    float* rs1  = sums;
    float* rs2  = sums + NROW;
    float* rbr  = sums + 2 * NROW;
    float* rbc  = sums + 3 * NROW;
    float* diag = sums + 4 * NROW;

    normalize_kernel<<<NROW / 4, 256, 0, stream>>>(h1, h2, z1b, z2b, diag,
                                                   rs1, rs2, rbr, rbc, out);

    expsum_kernel<<<GRID, 256, 0, stream>>>(z1b, z2b, rs1, rs2, rbr, rbc);

    finalize_kernel<<<NROW / 256, 256, 0, stream>>>(rs1, rs2, rbr, rbc, diag, out);
}

// Round 5
// 145.373 us; speedup vs baseline: 6.0369x; 6.0369x over previous
//
#include <hip/hip_runtime.h>
#include <math.h>

#define NROW 8192
#define DDIM 256
#define BM 128
#define BN 64           // column-half blocks: wave tile 64x32 -> 32 acc regs
#define BK 128
#define NT_SYM 2080     // 64*65/2 lower-triangular 128x128 logical tiles
#define NT_FULL 4096
#define NT_TOTAL (2 * NT_SYM + NT_FULL)   // 8256 logical tiles
#define GRID (2 * NT_TOTAL)               // 2 column-halves each

typedef __attribute__((ext_vector_type(4)))  float f32x4;
typedef __attribute__((ext_vector_type(16))) float f32x16;
typedef __attribute__((ext_vector_type(4)))  int   i32x4;
typedef __attribute__((ext_vector_type(8)))  int   i32x8;
typedef __attribute__((address_space(3))) unsigned int lds_u32;
typedef const __attribute__((address_space(1))) unsigned int glb_u32;

// DPP row_ror butterfly add: after ror 1,2,4,8 every lane of each 16-lane row
// holds the row sum. VALU pipe only — no DS traffic.
template <int CTRL>
static __device__ inline float dpp_ror_add(float v) {
    int s = __float_as_int(v);
    int r = __builtin_amdgcn_update_dpp(0, s, CTRL, 0xF, 0xF, true);
    return v + __int_as_float(r);
}
static __device__ inline float row16_sum(float v) {
    v = dpp_ror_add<0x121>(v);
    v = dpp_ror_add<0x122>(v);
    v = dpp_ror_add<0x124>(v);
    v = dpp_ror_add<0x128>(v);
    return v;
}

// Pack 4 floats -> 4 fp8 e4m3 bytes (HW cvt, OCP on gfx950 — self-consistent
// with the fp8 MFMA's decode).
static __device__ inline unsigned int pack_fp8x4(float a, float b, float c, float d) {
    int p = __builtin_amdgcn_cvt_pk_fp8_f32(a, b, 0, false);
    p = __builtin_amdgcn_cvt_pk_fp8_f32(c, d, p, true);
    return (unsigned int)p;
}

// One wave per row: L2-normalize H1/H2 rows, scale by sqrt(2*log2(e)) so the
// fp8 Gram entries come out as 2*log2(e)*s -> exp(2s) == exp2(acc).
// diag[row] = 2*dot(z1n,z2n) fp32 (exact). Zero-inits rowsums and out.
__global__ __launch_bounds__(256) void normalize_kernel(
        const float* __restrict__ h1, const float* __restrict__ h2,
        unsigned char* __restrict__ z1b, unsigned char* __restrict__ z2b,
        float* __restrict__ diag,
        float* __restrict__ rs1, float* __restrict__ rs2,
        float* __restrict__ rbr, float* __restrict__ rbc,
        float* __restrict__ out) {
    int wave = threadIdx.x >> 6;
    int lane = threadIdx.x & 63;
    int row  = blockIdx.x * 4 + wave;
    if (blockIdx.x == 0 && threadIdx.x == 0) out[0] = 0.f;
    const float4* p1 = (const float4*)(h1 + (size_t)row * DDIM);
    const float4* p2 = (const float4*)(h2 + (size_t)row * DDIM);
    float4 a = p1[lane];
    float4 b = p2[lane];
    float s1 = a.x*a.x + a.y*a.y + a.z*a.z + a.w*a.w;
    float s2 = b.x*b.x + b.y*b.y + b.z*b.z + b.w*b.w;
    #pragma unroll
    for (int m = 1; m < 64; m <<= 1) { s1 += __shfl_xor(s1, m); s2 += __shfl_xor(s2, m); }
    float r1 = 1.0f / fmaxf(sqrtf(s1), 1e-12f);
    float r2 = 1.0f / fmaxf(sqrtf(s2), 1e-12f);
    float n1x = a.x*r1, n1y = a.y*r1, n1z = a.z*r1, n1w = a.w*r1;
    float n2x = b.x*r2, n2y = b.y*r2, n2z = b.z*r2, n2w = b.w*r2;
    float dt = n1x*n2x + n1y*n2y + n1z*n2z + n1w*n2w;
    #pragma unroll
    for (int m = 1; m < 64; m <<= 1) dt += __shfl_xor(dt, m);
    if (lane == 0) {
        diag[row] = 2.0f * dt;
        rs1[row] = 0.f; rs2[row] = 0.f; rbr[row] = 0.f; rbc[row] = 0.f;
    }
    const float SC = 1.69864364f;   // sqrt(2 * log2(e))
    ((unsigned int*)(z1b + (size_t)row * DDIM))[lane] =
        pack_fp8x4(n1x*SC, n1y*SC, n1z*SC, n1w*SC);
    ((unsigned int*)(z2b + (size_t)row * DDIM))[lane] =
        pack_fp8x4(n2x*SC, n2y*SC, n2z*SC, n2w*SC);
}

// R8 = R7's compute structure (proven: 55% occupancy, scaled-MFMA pipe time
// ~13 us) + a proper reduction epilogue. R7's direct-atomic epilogue was the
// regression: 12.7M global atomics (WRITE_SIZE 41->225 MB), ~400-deep
// same-address RMW chains -> 850 us. Now: DPP/shfl wave reduction ->
// cross-wave combine in 1.5 KB LDS scratch -> 192 atomics per block
// (one lane per row/col), ~3.2M total = R4's harmless level.
//
// Block = 128x64 (column-half of a logical 128x128 tile), wave tile 64x32
// (acc = 2 x f32x16 = 32 regs), 6 blocks/CU (72 regs, 25.5 KB LDS).
// LDS granule swizzle: phys granule p of row r holds logical p^(r&7),
// applied on the DMA's global address; reads XOR the same key -> b128
// beats conflict-free.
__global__ __launch_bounds__(256, 6) void expsum_kernel(
        const unsigned char* __restrict__ z1, const unsigned char* __restrict__ z2,
        float* __restrict__ rs1, float* __restrict__ rs2,
        float* __restrict__ rbr, float* __restrict__ rbc) {
    int t  = blockIdx.x >> 1;
    int ch = blockIdx.x & 1;           // which 64-col half of the 128x128 tile
    int kind, tt;
    if (t < NT_SYM)            { kind = 0; tt = t; }
    else if (t < 2 * NT_SYM)   { kind = 1; tt = t - NT_SYM; }
    else                       { kind = 2; tt = t - 2 * NT_SYM; }

    int by, bx;
    const unsigned char *Ap, *Bp;
    float *rowsum, *colsum;
    if (kind == 2) {
        by = tt >> 6; bx = tt & 63;
        Ap = z1; Bp = z2; rowsum = rbr; colsum = rbc;
    } else {
        by = (int)((sqrtf(8.0f * (float)tt + 1.0f) - 1.0f) * 0.5f);
        while ((by + 1) * (by + 2) / 2 <= tt) ++by;
        while (by * (by + 1) / 2 > tt) --by;
        bx = tt - by * (by + 1) / 2;          // bx <= by
        const unsigned char* z = (kind == 0) ? z1 : z2;
        Ap = z; Bp = z;
        rowsum = (kind == 0) ? rs1 : rs2;
        colsum = (bx == by) ? nullptr : rowsum;
    }

    const int rt = by * BM;
    const int ct = bx * BM + ch * BN;    // global col base of this half

    __shared__ __align__(16) unsigned char lA[BM * BK];  // 16 KB
    __shared__ __align__(16) unsigned char lB[BN * BK];  // 8 KB
    __shared__ float lds_rp[2][BM];                      // [wc][row]  1 KB
    __shared__ float lds_cp[2][BN];                      // [wr][col] 512 B

    const int tid  = threadIdx.x;
    const int lane = tid & 63;
    const int wid  = tid >> 6;
    const int wr   = wid & 1;            // 64-row half
    const int wc   = wid >> 1;           // 32-col quarter (of the 64-col tile)
    const int l31  = lane & 31;
    const int kh   = lane >> 5;          // k-half of the 64-wide k-step

    // DMA lane mapping: 8 lanes per 128-B row, 8 rows per wave-instruction.
    const int srow = lane >> 3;          // row within 8-row group
    const int sgt  = lane & 7;           // physical 16B granule (= DMA slot)

    const int sw16 = (l31 & 7);          // row-swizzle key for reads

    const int aoff0 = (wr * 64 + l31) * BK;          // rows 0..31 of wave tile
    const int aoff1 = aoff0 + 32 * BK;               // rows 32..63
    const int boff  = (wc * 32 + l31) * BK;

    f32x16 acc0, acc1;
    #pragma unroll
    for (int r = 0; r < 16; ++r) { acc0[r] = 0.f; acc1[r] = 0.f; }

    for (int kt = 0; kt < DDIM; kt += BK) {
        // Stage A (128x128B: 16 DMAs, 4/wave) and B (64x128B: 8 DMAs, 2/wave).
        #pragma unroll
        for (int p = 0; p < 4; ++p) {
            int r0 = (p * 4 + wid) * 8;
            int r  = r0 + srow;
            int gg = sgt ^ (r & 7);
            const unsigned char* ga = Ap + (size_t)(rt + r) * DDIM + kt + gg * 16;
            __builtin_amdgcn_global_load_lds((glb_u32*)ga, (lds_u32*)(lA + r0 * BK), 16, 0, 0);
        }
        #pragma unroll
        for (int p = 0; p < 2; ++p) {
            int r0 = (p * 4 + wid) * 8;
            int r  = r0 + srow;
            int gg = sgt ^ (r & 7);
            const unsigned char* gb = Bp + (size_t)(ct + r) * DDIM + kt + gg * 16;
            __builtin_amdgcn_global_load_lds((glb_u32*)gb, (lds_u32*)(lB + r0 * BK), 16, 0, 0);
        }
        __syncthreads();
        #pragma unroll
        for (int ks = 0; ks < 2; ++ks) {            // 2 x K=64 per k-tile
            const int g0   = ks * 4 + kh * 2;       // logical even granule
            const int off0 = (g0 ^ sw16) * 16;
            const int off1 = off0 ^ 16;             // odd partner granule
            i32x4 alo0 = *(const i32x4*)(lA + aoff0 + off0);
            i32x4 ahi0 = *(const i32x4*)(lA + aoff0 + off1);
            i32x4 alo1 = *(const i32x4*)(lA + aoff1 + off0);
            i32x4 ahi1 = *(const i32x4*)(lA + aoff1 + off1);
            i32x4 blo  = *(const i32x4*)(lB + boff  + off0);
            i32x4 bhi  = *(const i32x4*)(lB + boff  + off1);
            i32x8 a0 = (i32x8){alo0[0], alo0[1], alo0[2], alo0[3],
                               ahi0[0], ahi0[1], ahi0[2], ahi0[3]};
            i32x8 a1 = (i32x8){alo1[0], alo1[1], alo1[2], alo1[3],
                               ahi1[0], ahi1[1], ahi1[2], ahi1[3]};
            i32x8 bv = (i32x8){blo[0], blo[1], blo[2], blo[3],
                               bhi[0], bhi[1], bhi[2], bhi[3]};
            acc0 = __builtin_amdgcn_mfma_scale_f32_32x32x64_f8f6f4(
                a0, bv, acc0, 0, 0, 0, 0x7F7F7F7F, 0, 0x7F7F7F7F);
            acc1 = __builtin_amdgcn_mfma_scale_f32_32x32x64_f8f6f4(
                a1, bv, acc1, 0, 0, 0, 0x7F7F7F7F, 0, 0x7F7F7F7F);
        }
        __syncthreads();
    }

    // C/D layout (32x32): col = lane&31, row = (reg&3) + 8*(reg>>2) + 4*kh.
    // acc = 2*log2e*s -> raw v_exp_f32 (inputs bounded ~|2.9|).
    // Wave-level: DPP row16 + shfl(16) -> full 32-col row sums in l31==0
    // lanes; col partials per lane, kh halves merged via shfl(32).
    // Cross-wave: tiny LDS scratch, then ONE atomic per row/col per block.
    float colpart = 0.f;
    #pragma unroll
    for (int r = 0; r < 16; ++r) {
        float e0 = __builtin_amdgcn_exp2f(acc0[r]);
        float e1 = __builtin_amdgcn_exp2f(acc1[r]);
        colpart += e0 + e1;
        float v0 = row16_sum(e0);
        v0 += __shfl_xor(v0, 16);
        float v1 = row16_sum(e1);
        v1 += __shfl_xor(v1, 16);
        if (l31 == 0) {                       // lanes 0 (kh=0) and 32 (kh=1)
            int rloc = wr * 64 + 4 * kh + (r & 3) + 8 * (r >> 2);
            lds_rp[wc][rloc]      = v0;
            lds_rp[wc][rloc + 32] = v1;
        }
    }
    float cp = colpart + __shfl_xor(colpart, 32);   // merge kh row-halves
    if (lane < 32) lds_cp[wr][wc * 32 + l31] = cp;
    __syncthreads();
    if (tid < BM) {
        atomicAdd(&rowsum[rt + tid], lds_rp[0][tid] + lds_rp[1][tid]);
    } else if (colsum && tid < BM + BN) {
        int c = tid - BM;
        atomicAdd(&colsum[ct + c], lds_cp[0][c] + lds_cp[1][c]);
    }
}

// 32 blocks x 256 threads, one row each; block-reduce then one atomicAdd.
__global__ __launch_bounds__(256) void finalize_kernel(
        const float* __restrict__ rs1, const float* __restrict__ rs2,
        const float* __restrict__ rbr, const float* __restrict__ rbc,
        const float* __restrict__ diag, float* __restrict__ out) {
    __shared__ float s4[4];
    const float E2 = 7.38905609893065f;   // exp(1/tau), tau=0.5
    int i = blockIdx.x * 256 + threadIdx.x;
    float den1 = rs1[i] + rbr[i] - E2;
    float den2 = rs2[i] + rbc[i] - E2;
    float v = 0.5f * (logf(den1) + logf(den2)) - diag[i];
    #pragma unroll
    for (int m = 1; m < 64; m <<= 1) v += __shfl_xor(v, m);
    if ((threadIdx.x & 63) == 0) s4[threadIdx.x >> 6] = v;
    __syncthreads();
    if (threadIdx.x == 0) {
        float t = (s4[0] + s4[1] + s4[2] + s4[3]) * (1.0f / (float)NROW);
        atomicAdd(out, t);
    }
}

extern "C" void kernel_launch(void* const* d_in, const int* in_sizes, int n_in,
                              void* d_out, int out_size, void* d_ws, size_t ws_size,
                              hipStream_t stream) {
    const float* h1 = (const float*)d_in[0];
    const float* h2 = (const float*)d_in[1];
    float* out = (float*)d_out;

    char* ws = (char*)d_ws;
    unsigned char* z1b = (unsigned char*)ws;                             // 2 MB
    unsigned char* z2b = (unsigned char*)(ws + (size_t)NROW * DDIM);     // 2 MB
    float* sums = (float*)(ws + (size_t)2 * NROW * DDIM);
    float* rs1  = sums;
    float* rs2  = sums + NROW;
    float* rbr  = sums + 2 * NROW;
    float* rbc  = sums + 3 * NROW;
    float* diag = sums + 4 * NROW;

    normalize_kernel<<<NROW / 4, 256, 0, stream>>>(h1, h2, z1b, z2b, diag,
                                                   rs1, rs2, rbr, rbc, out);

    expsum_kernel<<<GRID, 256, 0, stream>>>(z1b, z2b, rs1, rs2, rbr, rbc);

    finalize_kernel<<<NROW / 256, 256, 0, stream>>>(rs1, rs2, rbr, rbc, diag, out);
}